// Round 8
// baseline (116.788 us; speedup 1.0000x reference)
//
#include <hip/hip_runtime.h>
#include <hip/hip_fp16.h>
#include <stdint.h>

#define D0 1024
#define D1 8192
#define D2 8192
#define D3 10240
#define B_ROWS 4096

// softmax(w[16]) @ OP_COEF -> (c0,c1,c2,c3)
__device__ __forceinline__ float4 softmax_coef(const float* __restrict__ w) {
    const float4* wv = (const float4*)w;
    float4 q0 = wv[0], q1 = wv[1], q2 = wv[2], q3 = wv[3];
    float wa[16] = {q0.x, q0.y, q0.z, q0.w, q1.x, q1.y, q1.z, q1.w,
                    q2.x, q2.y, q2.z, q2.w, q3.x, q3.y, q3.z, q3.w};
    float m = wa[0];
#pragma unroll
    for (int i = 1; i < 16; ++i) m = fmaxf(m, wa[i]);
    float e[16], s = 0.f;
#pragma unroll
    for (int i = 0; i < 16; ++i) { e[i] = __expf(wa[i] - m); s += e[i]; }
    float inv = 1.f / s;
    static constexpr float OPC[16][4] = {
        {0.f, 0.f, 0.f, 0.f}, {0.f, 0.f, 0.f, 1.f}, {0.f, 1.f, 0.f, -1.f}, {0.f, 1.f, 0.f, 0.f},
        {0.f, 0.f, 1.f, -1.f}, {0.f, 0.f, 1.f, 0.f}, {0.f, 1.f, 1.f, -2.f}, {0.f, 1.f, 1.f, -1.f},
        {1.f, -1.f, -1.f, 1.f}, {1.f, -1.f, -1.f, 2.f}, {1.f, 0.f, -1.f, 0.f}, {1.f, 0.f, -1.f, 1.f},
        {1.f, -1.f, 0.f, 0.f}, {1.f, -1.f, 0.f, 1.f}, {1.f, 0.f, 0.f, -1.f}, {1.f, 0.f, 0.f, 0.f}};
    float c0 = 0.f, c1 = 0.f, c2 = 0.f, c3 = 0.f;
#pragma unroll
    for (int i = 0; i < 16; ++i) {  // 0/±1/±2 multiplies fold at compile time
        float p = e[i] * inv;
        c0 += p * OPC[i][0];
        c1 += p * OPC[i][1];
        c2 += p * OPC[i][2];
        c3 += p * OPC[i][3];
    }
    return make_float4(c0, c1, c2, c3);
}

__device__ __forceinline__ uint2 pack_coef(float4 c) {
    uint2 r;
    r.x = __builtin_bit_cast(uint32_t, __floats2half2_rn(c.x, c.y));
    r.y = __builtin_bit_cast(uint32_t, __floats2half2_rn(c.z, c.w));
    return r;
}

// prep: FULLY denormalized per-layer-3-gate records (layers 1+2 folded in).
// For L3 gate g with L2 parents P0=ia3[g], P1=ib3[g], and P_i's L1 parents
// A_i=ia2[P_i], B_i=ib2[P_i]:
//   m0 = (xi(A0), xi(B0), xi(A1), xi(B1))  xi(L) = packed x byte-offsets
//                                          (ia1[L]<<3 | ib1[L]<<3 <<16)
//   m1 = coefs of A0,B0;  m2 = coefs of A1,B1;  m3 = coefs of P0,P1
//   m4 = own coefs (uint2)
__global__ __launch_bounds__(256) void prep_kernel(
    const float* __restrict__ w1, const float* __restrict__ w2,
    const float* __restrict__ w3,
    const int* __restrict__ ia1, const int* __restrict__ ib1,
    const int* __restrict__ ia2, const int* __restrict__ ib2,
    const int* __restrict__ ia3, const int* __restrict__ ib3,
    uint4* __restrict__ M0, uint4* __restrict__ M1, uint4* __restrict__ M2,
    uint4* __restrict__ M3, uint2* __restrict__ M4) {
    int g = blockIdx.x * 256 + threadIdx.x;  // grid = D3/256
    int p0 = ia3[g], p1 = ib3[g];
    int a0 = ia2[p0], b0 = ib2[p0];
    int a1 = ia2[p1], b1 = ib2[p1];
    uint32_t x0 = (uint32_t)(ia1[a0] << 3) | ((uint32_t)(ib1[a0] << 3) << 16);
    uint32_t x1 = (uint32_t)(ia1[b0] << 3) | ((uint32_t)(ib1[b0] << 3) << 16);
    uint32_t x2 = (uint32_t)(ia1[a1] << 3) | ((uint32_t)(ib1[a1] << 3) << 16);
    uint32_t x3 = (uint32_t)(ia1[b1] << 3) | ((uint32_t)(ib1[b1] << 3) << 16);
    M0[g] = make_uint4(x0, x1, x2, x3);
    uint2 cA0 = pack_coef(softmax_coef(w1 + (size_t)a0 * 16));
    uint2 cB0 = pack_coef(softmax_coef(w1 + (size_t)b0 * 16));
    M1[g] = make_uint4(cA0.x, cA0.y, cB0.x, cB0.y);
    uint2 cA1 = pack_coef(softmax_coef(w1 + (size_t)a1 * 16));
    uint2 cB1 = pack_coef(softmax_coef(w1 + (size_t)b1 * 16));
    M2[g] = make_uint4(cA1.x, cA1.y, cB1.x, cB1.y);
    uint2 cP0 = pack_coef(softmax_coef(w2 + (size_t)p0 * 16));
    uint2 cP1 = pack_coef(softmax_coef(w2 + (size_t)p1 * 16));
    M3[g] = make_uint4(cP0.x, cP0.y, cP1.x, cP1.y);
    M4[g] = pack_coef(softmax_coef(w3 + (size_t)g * 16));
}

// One gate for 4 rows (2x half2); compact coefs (c0c1, c2c3) broadcast here.
// h = (c0 + c2*b) + a*(c1 + c3*b)
__device__ __forceinline__ uint2 gate4(uint2 av, uint2 bv, uint2 cf) {
    __half2 p = __builtin_bit_cast(__half2, cf.x);  // (c0,c1)
    __half2 q = __builtin_bit_cast(__half2, cf.y);  // (c2,c3)
    __half2 c0 = __low2half2(p), c1 = __high2half2(p);
    __half2 c2 = __low2half2(q), c3 = __high2half2(q);
    __half2 a01 = __builtin_bit_cast(__half2, av.x);
    __half2 a23 = __builtin_bit_cast(__half2, av.y);
    __half2 b01 = __builtin_bit_cast(__half2, bv.x);
    __half2 b23 = __builtin_bit_cast(__half2, bv.y);
    __half2 h01 = __hfma2(a01, __hfma2(b01, c3, c1), __hfma2(b01, c2, c0));
    __half2 h23 = __hfma2(a23, __hfma2(b23, c3, c1), __hfma2(b23, c2, c0));
    uint2 r;
    r.x = __builtin_bit_cast(uint32_t, h01);
    r.y = __builtin_bit_cast(uint32_t, h23);
    return r;
}

// Fully-fused kernel: each layer-3 gate recomputes its whole 7-gate subtree
// from xb. ONE barrier, 8.4 KB static LDS, 512-thr blocks, 4 rows/block ->
// 4 independent blocks/CU (32 waves) with no h2 materialization phase.
__global__ __launch_bounds__(512, 8) void fused_kernel(
    const float* __restrict__ x, const uint4* __restrict__ M0,
    const uint4* __restrict__ M1, const uint4* __restrict__ M2,
    const uint4* __restrict__ M3, const uint2* __restrict__ M4,
    float* __restrict__ out) {
    __shared__ char sm[8192 + 160];
    uint2* xb = (uint2*)sm;                 // 1024 gates x 4 rows fp16
    float* csum = (float*)(sm + 8192);      // [10 classes][4 rows]

    const int t = threadIdx.x;
    const int rowbase = blockIdx.x << 2;
    const int wv = t >> 6, lane = t & 63;
    const int gbase = wv * 1280;            // 8 waves x 1280 = 10240 gates

    // Prefetch iter-0 gather-address stream (drains during stage A+barrier).
    uint4 m0_n = M0[gbase + lane];

    // Stage A: 4 rows of x -> fp16, row-interleaved into xb (coalesced).
    {
        const float* xp = x + (size_t)rowbase * D0;
#pragma unroll
        for (int c = t; c < D0; c += 512) {
            uint2 v;
            v.x = __builtin_bit_cast(uint32_t, __floats2half2_rn(xp[c], xp[D0 + c]));
            v.y = __builtin_bit_cast(uint32_t, __floats2half2_rn(xp[2 * D0 + c], xp[3 * D0 + c]));
            xb[c] = v;
        }
    }
    if (t < 40) csum[t] = 0.f;
    __syncthreads();

    // Main loop: 20 iters x 64 lanes = 1280 gates per wave. Each 64-gate
    // chunk lies in one class (64 | 1024 boundaries) -> wave-uniform select.
    const int cA = gbase >> 10;
    const int bnd = (cA + 1) << 10;
    float s0[4] = {0.f, 0.f, 0.f, 0.f};
    float s1[4] = {0.f, 0.f, 0.f, 0.f};
#pragma unroll
    for (int j = 0; j < 20; ++j) {
        int g = gbase + (j << 6) + lane;
        uint4 m0 = m0_n;
        if (j < 19) m0_n = M0[g + 64];
        // 8 independent b64 gathers in flight.
        uint2 aa = *(const uint2*)(sm + (m0.x & 0xffffu));
        uint2 ab = *(const uint2*)(sm + (m0.x >> 16));
        uint2 ba = *(const uint2*)(sm + (m0.y & 0xffffu));
        uint2 bb = *(const uint2*)(sm + (m0.y >> 16));
        uint2 ca = *(const uint2*)(sm + (m0.z & 0xffffu));
        uint2 cb = *(const uint2*)(sm + (m0.z >> 16));
        uint2 da = *(const uint2*)(sm + (m0.w & 0xffffu));
        uint2 db = *(const uint2*)(sm + (m0.w >> 16));
        uint4 m1 = M1[g];
        uint4 m2 = M2[g];
        uint4 m3 = M3[g];
        uint2 m4 = M4[g];
        // 7-gate subtree: 4 L1 gates, 2 L2 gates, 1 L3 gate.
        uint2 hA0 = gate4(aa, ab, make_uint2(m1.x, m1.y));
        uint2 hB0 = gate4(ba, bb, make_uint2(m1.z, m1.w));
        uint2 hA1 = gate4(ca, cb, make_uint2(m2.x, m2.y));
        uint2 hB1 = gate4(da, db, make_uint2(m2.z, m2.w));
        uint2 hP0 = gate4(hA0, hB0, make_uint2(m3.x, m3.y));
        uint2 hP1 = gate4(hA1, hB1, make_uint2(m3.z, m3.w));
        uint2 h = gate4(hP0, hP1, m4);
        __half2 h01 = __builtin_bit_cast(__half2, h.x);
        __half2 h23 = __builtin_bit_cast(__half2, h.y);
        float f0 = __low2float(h01), f1 = __high2float(h01);
        float f2 = __low2float(h23), f3 = __high2float(h23);
        if (gbase + (j << 6) < bnd) {
            s0[0] += f0; s0[1] += f1; s0[2] += f2; s0[3] += f3;
        } else {
            s1[0] += f0; s1[1] += f1; s1[2] += f2; s1[3] += f3;
        }
    }
    // Wave butterfly reduction (64 lanes).
#pragma unroll
    for (int m = 1; m < 64; m <<= 1) {
#pragma unroll
        for (int r = 0; r < 4; ++r) {
            s0[r] += __shfl_xor(s0[r], m, 64);
            s1[r] += __shfl_xor(s1[r], m, 64);
        }
    }
    if (lane == 0) {
#pragma unroll
        for (int r = 0; r < 4; ++r) atomicAdd(&csum[cA * 4 + r], s0[r]);
        if (gbase + 1280 > bnd) {
#pragma unroll
            for (int r = 0; r < 4; ++r) atomicAdd(&csum[(cA + 1) * 4 + r], s1[r]);
        }
    }
    __syncthreads();

    if (t < 40) {
        int c = t >> 2, r = t & 3;
        out[(size_t)(rowbase + r) * 10 + c] = csum[t] * (1.0f / 30.0f);
    }
}

extern "C" void kernel_launch(void* const* d_in, const int* in_sizes, int n_in,
                              void* d_out, int out_size, void* d_ws, size_t ws_size,
                              hipStream_t stream) {
    const float* x = (const float*)d_in[0];
    const float* w1 = (const float*)d_in[1];
    const float* w2 = (const float*)d_in[2];
    const float* w3 = (const float*)d_in[3];
    const int* ia1 = (const int*)d_in[4];
    const int* ib1 = (const int*)d_in[5];
    const int* ia2 = (const int*)d_in[6];
    const int* ib2 = (const int*)d_in[7];
    const int* ia3 = (const int*)d_in[8];
    const int* ib3 = (const int*)d_in[9];
    float* out = (float*)d_out;

    // Workspace: M0..M3 160K each | M4 80K (all 16B-aligned). 720 KB total;
    // per-XCD-L2-resident during the fused kernel.
    char* p = (char*)d_ws;
    uint4* M0 = (uint4*)p;  p += (size_t)D3 * 16;
    uint4* M1 = (uint4*)p;  p += (size_t)D3 * 16;
    uint4* M2 = (uint4*)p;  p += (size_t)D3 * 16;
    uint4* M3 = (uint4*)p;  p += (size_t)D3 * 16;
    uint2* M4 = (uint2*)p;

    prep_kernel<<<D3 / 256, 256, 0, stream>>>(
        w1, w2, w3, ia1, ib1, ia2, ib2, ia3, ib3, M0, M1, M2, M3, M4);
    fused_kernel<<<B_ROWS / 4, 512, 0, stream>>>(x, M0, M1, M2, M3, M4, out);
}

// Round 9
// 104.435 us; speedup vs baseline: 1.1183x; 1.1183x over previous
//
#include <hip/hip_runtime.h>
#include <hip/hip_fp16.h>
#include <stdint.h>

#define D0 1024
#define D1 8192
#define D2 8192
#define D3 10240
#define B_ROWS 4096

// LDS layout (bytes), 8 rows/block fp16 row-interleaved [gate][8 rows]=16B:
// xb 16K | h2 128K | csum 320 -> 144.3 KB, 1 block/CU (wave-capped anyway at
// 1024 thr; trades waves 32->16 for half the sequential blocks per CU).
#define SM_XB     0
#define SM_H2     16384
#define SM_CSUM   (16384 + 131072)
#define SM_BYTES  (16384 + 131072 + 320)

// softmax(w[16]) @ OP_COEF -> (c0,c1,c2,c3)
__device__ __forceinline__ float4 softmax_coef(const float* __restrict__ w) {
    const float4* wv = (const float4*)w;
    float4 q0 = wv[0], q1 = wv[1], q2 = wv[2], q3 = wv[3];
    float wa[16] = {q0.x, q0.y, q0.z, q0.w, q1.x, q1.y, q1.z, q1.w,
                    q2.x, q2.y, q2.z, q2.w, q3.x, q3.y, q3.z, q3.w};
    float m = wa[0];
#pragma unroll
    for (int i = 1; i < 16; ++i) m = fmaxf(m, wa[i]);
    float e[16], s = 0.f;
#pragma unroll
    for (int i = 0; i < 16; ++i) { e[i] = __expf(wa[i] - m); s += e[i]; }
    float inv = 1.f / s;
    static constexpr float OPC[16][4] = {
        {0.f, 0.f, 0.f, 0.f}, {0.f, 0.f, 0.f, 1.f}, {0.f, 1.f, 0.f, -1.f}, {0.f, 1.f, 0.f, 0.f},
        {0.f, 0.f, 1.f, -1.f}, {0.f, 0.f, 1.f, 0.f}, {0.f, 1.f, 1.f, -2.f}, {0.f, 1.f, 1.f, -1.f},
        {1.f, -1.f, -1.f, 1.f}, {1.f, -1.f, -1.f, 2.f}, {1.f, 0.f, -1.f, 0.f}, {1.f, 0.f, -1.f, 1.f},
        {1.f, -1.f, 0.f, 0.f}, {1.f, -1.f, 0.f, 1.f}, {1.f, 0.f, 0.f, -1.f}, {1.f, 0.f, 0.f, 0.f}};
    float c0 = 0.f, c1 = 0.f, c2 = 0.f, c3 = 0.f;
#pragma unroll
    for (int i = 0; i < 16; ++i) {  // 0/±1/±2 multiplies fold at compile time
        float p = e[i] * inv;
        c0 += p * OPC[i][0];
        c1 += p * OPC[i][1];
        c2 += p * OPC[i][2];
        c3 += p * OPC[i][3];
    }
    return make_float4(c0, c1, c2, c3);
}

__device__ __forceinline__ uint2 pack_coef(float4 c) {
    uint2 r;
    r.x = __builtin_bit_cast(uint32_t, __floats2half2_rn(c.x, c.y));
    r.y = __builtin_bit_cast(uint32_t, __floats2half2_rn(c.z, c.w));
    return r;
}

// prep: run-invariant metadata, packed for dwordx4 consumption.
//  bcM1[g] = (xiA, xiB, coO.lo, coO.hi)  xi* = packed x BYTE offsets (<<4,
//  bcM2[g] = (cA.lo, cA.hi, cB.lo, cB.hi) fits u16: max 1023*16)
//  d3M[g]  = (ei, co.lo, co.hi, 0)       ei = packed h2 ELEMENT indices
//                                        (byte offset would overflow u16)
__global__ __launch_bounds__(64) void prep_kernel(
    const float* __restrict__ w1, const float* __restrict__ w2,
    const float* __restrict__ w3,
    const int* __restrict__ ia1, const int* __restrict__ ib1,
    const int* __restrict__ ia2, const int* __restrict__ ib2,
    const int* __restrict__ ia3, const int* __restrict__ ib3,
    uint4* __restrict__ bcM1, uint4* __restrict__ bcM2,
    uint4* __restrict__ d3M) {
    int G = blockIdx.x * 64 + threadIdx.x;  // grid = (D2 + D3) / 64
    if (G < D2) {
        int g = G;
        int pa = ia2[g], pb = ib2[g];
        float4 cO = softmax_coef(w2 + (size_t)g * 16);
        float4 cA = softmax_coef(w1 + (size_t)pa * 16);
        float4 cB = softmax_coef(w1 + (size_t)pb * 16);
        uint32_t xiA = (uint32_t)(ia1[pa] << 4) | ((uint32_t)(ib1[pa] << 4) << 16);
        uint32_t xiB = (uint32_t)(ia1[pb] << 4) | ((uint32_t)(ib1[pb] << 4) << 16);
        uint2 o = pack_coef(cO), a = pack_coef(cA), b = pack_coef(cB);
        bcM1[g] = make_uint4(xiA, xiB, o.x, o.y);
        bcM2[g] = make_uint4(a.x, a.y, b.x, b.y);
    } else {
        int g = G - D2;
        float4 cO = softmax_coef(w3 + (size_t)g * 16);
        uint2 o = pack_coef(cO);
        uint32_t ei = (uint32_t)ia3[g] | ((uint32_t)ib3[g] << 16);
        d3M[g] = make_uint4(ei, o.x, o.y, 0u);
    }
}

// One gate for 8 rows (4x half2); compact coefs (c0c1, c2c3) broadcast here.
// h = (c0 + c2*b) + a*(c1 + c3*b): 12 v_pk_fma_f16 + 4 extracts.
__device__ __forceinline__ uint4 gate8(uint4 av, uint4 bv, uint2 cf) {
    __half2 p = __builtin_bit_cast(__half2, cf.x);  // (c0,c1)
    __half2 q = __builtin_bit_cast(__half2, cf.y);  // (c2,c3)
    __half2 c0 = __low2half2(p), c1 = __high2half2(p);
    __half2 c2 = __low2half2(q), c3 = __high2half2(q);
    uint4 r;
#pragma unroll
    for (int i = 0; i < 4; ++i) {
        __half2 a = __builtin_bit_cast(__half2, (&av.x)[i]);
        __half2 b = __builtin_bit_cast(__half2, (&bv.x)[i]);
        __half2 h = __hfma2(a, __hfma2(b, c3, c1), __hfma2(b, c2, c0));
        (&r.x)[i] = __builtin_bit_cast(uint32_t, h);
    }
    return r;
}

// Fused: layers 1+2 fused, then layer 3 + group-sum. One block = 8 rows,
// activations [gate][8 rows] fp16 (16 B) -> every gather is one
// ds_read_b128. Half the blocks of the 4-row shape: half the per-CU
// barrier/stage-A/tail overhead and ~20% fewer LDS cycles per row.
__global__ __launch_bounds__(1024, 4) void fused_kernel(
    const float* __restrict__ x, const uint4* __restrict__ bcM1,
    const uint4* __restrict__ bcM2, const uint4* __restrict__ d3M,
    float* __restrict__ out) {
    extern __shared__ char sm[];
    uint4* xb = (uint4*)(sm + SM_XB);
    float* csum = (float*)(sm + SM_CSUM);

    const int t = threadIdx.x;
    const int rowbase = blockIdx.x << 3;  // 8 rows per block
    const int tg = t << 1;  // first gate of this thread's pair

    // Preload iter-0 index metadata (latency hidden behind stage A + barrier).
    uint4 m1a_n = bcM1[tg];
    uint4 m1b_n = bcM1[tg + 1];

    // Stage A: 8 rows of x -> fp16, row-interleaved into xb (16 B/gate).
    {
        const float* xp = x + (size_t)rowbase * D0 + t;
        uint4 v;
#pragma unroll
        for (int i = 0; i < 4; ++i) {
            float va = xp[(size_t)(2 * i) * D0];
            float vb = xp[(size_t)(2 * i + 1) * D0];
            (&v.x)[i] = __builtin_bit_cast(uint32_t, __floats2half2_rn(va, vb));
        }
        xb[t] = v;
    }
    if (t < 80) csum[t] = 0.f;
    __syncthreads();

    // Stage BC: fused layers 1+2, 2 gates/thread/iter, 4 iters covers 8192.
#pragma unroll
    for (int k = 0; k < 4; ++k) {
        uint4 m1a = m1a_n, m1b = m1b_n;
        int g = tg + (k << 11);
        uint4 m2a = bcM2[g];
        uint4 m2b = bcM2[g + 1];
        if (k < 3) {  // depth-2 prefetch of the gather-address stream
            int gn = tg + ((k + 1) << 11);
            m1a_n = bcM1[gn];
            m1b_n = bcM1[gn + 1];
        }
        // 8 independent b128 gathers in flight.
        uint4 aa0 = *(const uint4*)(sm + (m1a.x & 0xffffu));
        uint4 ab0 = *(const uint4*)(sm + (m1a.x >> 16));
        uint4 ba0 = *(const uint4*)(sm + (m1a.y & 0xffffu));
        uint4 bb0 = *(const uint4*)(sm + (m1a.y >> 16));
        uint4 aa1 = *(const uint4*)(sm + (m1b.x & 0xffffu));
        uint4 ab1 = *(const uint4*)(sm + (m1b.x >> 16));
        uint4 ba1 = *(const uint4*)(sm + (m1b.y & 0xffffu));
        uint4 bb1 = *(const uint4*)(sm + (m1b.y >> 16));
        uint4 h0 = gate8(gate8(aa0, ab0, make_uint2(m2a.x, m2a.y)),
                         gate8(ba0, bb0, make_uint2(m2a.z, m2a.w)),
                         make_uint2(m1a.z, m1a.w));
        uint4 h1v = gate8(gate8(aa1, ab1, make_uint2(m2b.x, m2b.y)),
                          gate8(ba1, bb1, make_uint2(m2b.z, m2b.w)),
                          make_uint2(m1b.z, m1b.w));
        *(uint4*)(sm + SM_H2 + ((uint32_t)g << 4)) = h0;
        *(uint4*)(sm + SM_H2 + ((uint32_t)(g + 1) << 4)) = h1v;
    }
    __syncthreads();

    // Stage D: layer 3 + grouped sum, 2 gates/lane/iter, 5 iters x 128 gates.
    // Each 128-gate chunk lies entirely within one class (128 | 1024).
    {
        const int wv = t >> 6, lane = t & 63;
        const int gbase = wv * 640;
        const int cA = gbase >> 10;
        const int bnd = (cA + 1) << 10;
        float s0[8] = {0.f, 0.f, 0.f, 0.f, 0.f, 0.f, 0.f, 0.f};
        float s1[8] = {0.f, 0.f, 0.f, 0.f, 0.f, 0.f, 0.f, 0.f};
#pragma unroll
        for (int j = 0; j < 5; ++j) {
            int gc = gbase + (j << 7);
            int g = gc + (lane << 1);
            uint4 ma = d3M[g];
            uint4 mb = d3M[g + 1];
            uint4 av0 = *(const uint4*)(sm + SM_H2 + ((ma.x & 0xffffu) << 4));
            uint4 bv0 = *(const uint4*)(sm + SM_H2 + ((ma.x >> 16) << 4));
            uint4 av1 = *(const uint4*)(sm + SM_H2 + ((mb.x & 0xffffu) << 4));
            uint4 bv1 = *(const uint4*)(sm + SM_H2 + ((mb.x >> 16) << 4));
            uint4 h0 = gate8(av0, bv0, make_uint2(ma.y, ma.z));
            uint4 h1v = gate8(av1, bv1, make_uint2(mb.y, mb.z));
            float* s = (gc < bnd) ? s0 : s1;  // wave-uniform select
#pragma unroll
            for (int i = 0; i < 4; ++i) {
                __half2 pr = __hadd2(__builtin_bit_cast(__half2, (&h0.x)[i]),
                                     __builtin_bit_cast(__half2, (&h1v.x)[i]));
                s[2 * i] += __low2float(pr);
                s[2 * i + 1] += __high2float(pr);
            }
        }
#pragma unroll
        for (int m = 1; m < 64; m <<= 1) {
#pragma unroll
            for (int r = 0; r < 8; ++r) {
                s0[r] += __shfl_xor(s0[r], m, 64);
                s1[r] += __shfl_xor(s1[r], m, 64);
            }
        }
        if (lane == 0) {
#pragma unroll
            for (int r = 0; r < 8; ++r) atomicAdd(&csum[cA * 8 + r], s0[r]);
            if (gbase + 640 > bnd) {
#pragma unroll
                for (int r = 0; r < 8; ++r) atomicAdd(&csum[(cA + 1) * 8 + r], s1[r]);
            }
        }
    }
    __syncthreads();

    if (t < 80) {
        int c = t >> 3, r = t & 7;
        out[(size_t)(rowbase + r) * 10 + c] = csum[t] * (1.0f / 30.0f);
    }
}

extern "C" void kernel_launch(void* const* d_in, const int* in_sizes, int n_in,
                              void* d_out, int out_size, void* d_ws, size_t ws_size,
                              hipStream_t stream) {
    const float* x = (const float*)d_in[0];
    const float* w1 = (const float*)d_in[1];
    const float* w2 = (const float*)d_in[2];
    const float* w3 = (const float*)d_in[3];
    const int* ia1 = (const int*)d_in[4];
    const int* ib1 = (const int*)d_in[5];
    const int* ia2 = (const int*)d_in[6];
    const int* ib2 = (const int*)d_in[7];
    const int* ia3 = (const int*)d_in[8];
    const int* ib3 = (const int*)d_in[9];
    float* out = (float*)d_out;

    // Workspace: bcM1 128K | bcM2 128K | d3M 160K (all 16B-aligned).
    char* p = (char*)d_ws;
    uint4* bcM1 = (uint4*)p;    p += (size_t)D2 * 16;
    uint4* bcM2 = (uint4*)p;    p += (size_t)D2 * 16;
    uint4* d3M = (uint4*)p;

    // >64KB dynamic LDS opt-in (host-side; graph-capture safe). 144.3 KB
    // fits the 160 KB/CU pool.
    hipFuncSetAttribute(reinterpret_cast<const void*>(fused_kernel),
                        hipFuncAttributeMaxDynamicSharedMemorySize, SM_BYTES);

    prep_kernel<<<(D2 + D3) / 64, 64, 0, stream>>>(
        w1, w2, w3, ia1, ib1, ia2, ib2, ia3, ib3, bcM1, bcM2, d3M);
    fused_kernel<<<B_ROWS / 8, 1024, SM_BYTES, stream>>>(x, bcM1, bcM2, d3M, out);
}